// Round 6
// baseline (1786.096 us; speedup 1.0000x reference)
//
#include <hip/hip_runtime.h>

typedef _Float16 f16;
typedef _Float16 f16x2 __attribute__((ext_vector_type(2)));
typedef _Float16 f16x8 __attribute__((ext_vector_type(8)));
typedef float f32x4 __attribute__((ext_vector_type(4)));
typedef unsigned int u32;

// ---------- sizes ----------
// B=256, W=512, FEAT=128, TIME=32, OV=32, IN=192, HG=256, HL=128, OG=128, OL=64
static constexpr size_t NROWS = 131072;
static constexpr int TC = 64;
static constexpr int NCHUNK = 8;   // 512 / TC
static constexpr size_t CROWS = 256 * TC;  // rows per chunk = 16384

// inp is B-MAJOR: row (b*512 + t), 192 f16 (96 u32). xbuf rows m-order: m = tt*256 + b.
static constexpr size_t O_INP = 0;
static constexpr size_t SZ_INP = NROWS * 192 * 2;
static constexpr size_t O_XB  = O_INP + SZ_INP;
static constexpr size_t SZ_XB = CROWS * 1152 * 2;
static constexpr size_t O_HG  = O_XB + SZ_XB;
static constexpr size_t SZ_HG = NROWS * 256 * 2;
static constexpr size_t O_HL  = O_HG + SZ_HG;
static constexpr size_t SZ_HL = NROWS * 128 * 2;
static constexpr size_t O_WF  = O_HL + SZ_HL;
static constexpr size_t SZ_WF = 1152 * 192 * 2;
static constexpr size_t O_BF  = O_WF + SZ_WF;
static constexpr size_t SZ_BF = 1152 * 4;
static constexpr size_t O_WHG = O_BF + SZ_BF;     // whh_g thread-interleaved [128][768] u32
static constexpr size_t SZ_WHG = 128 * 768 * 4;
static constexpr size_t O_WHL = O_WHG + SZ_WHG;   // whh_l thread-interleaved [64][384] u32
static constexpr size_t SZ_WHL = 64 * 384 * 4;
static constexpr size_t O_WG  = O_WHL + SZ_WHL;
static constexpr size_t SZ_WG = 128 * 256 * 2;
static constexpr size_t O_WL  = O_WG + SZ_WG;
static constexpr size_t SZ_WL = 64 * 128 * 2;
static constexpr size_t O_HGF = O_WL + SZ_WL;
static constexpr size_t SZ_HGF = 256 * 256 * 4;
static constexpr size_t O_HGP = O_HGF + SZ_HGF;
static constexpr size_t SZ_HGP = 256 * 128 * 4;
static constexpr size_t O_HLF = O_HGP + SZ_HGP;
static constexpr size_t SZ_HLF = 256 * 128 * 4;
static constexpr size_t O_HLP = O_HLF + SZ_HLF;
static constexpr size_t SZ_HLP = 256 * 64 * 4;
static constexpr size_t WS_NEED = O_HLP + SZ_HLP; // ~181.5 MiB

// ---------- helpers ----------
__device__ inline u32 pk2f(float lo, float hi) {
  f16x2 t; t.x = (f16)lo; t.y = (f16)hi;
  return __builtin_bit_cast(u32, t);
}

#if defined(__has_builtin)
#if __has_builtin(__builtin_amdgcn_fdot2)
#define HAVE_FDOT2 1
#endif
#endif

__device__ inline float dot2f(u32 w, u32 h, float c) {
#ifdef HAVE_FDOT2
  return __builtin_amdgcn_fdot2(__builtin_bit_cast(f16x2, w),
                                __builtin_bit_cast(f16x2, h), c, false);
#else
  f16x2 a = __builtin_bit_cast(f16x2, w);
  f16x2 b = __builtin_bit_cast(f16x2, h);
  return c + (float)a.x * (float)b.x + (float)a.y * (float)b.y;
#endif
}

__device__ inline float sigf(float x) { return 1.f / (1.f + __expf(-x)); }
__device__ inline float tanhf_fast(float x) { return 1.f - 2.f / (1.f + __expf(2.f * x)); }

// ---------- prep: weight conversion/packing ----------
// Scan weights are THREAD-INTERLEAVED for the 4-row x quarter-K split:
// thread j (g=j>>2, s=j&3) owns rows 4g+m (m=0..3), h-u32 slice u = s*Q + q.
// whhg[i*768 + j], i = m*32 + q (Q=32): pk2(Whh_g[(4g+m)*256 + 2u], [2u+1])
// whhl[i*384 + j], i = m*16 + q (Q=16): pk2(Whh_l[(4g+m)*128 + 2u], [2u+1])
__global__ void prep_k(const float* __restrict__ Wih_g, const float* __restrict__ Wih_l,
                       const float* __restrict__ bih_g, const float* __restrict__ bih_l,
                       const float* __restrict__ Whh_g, const float* __restrict__ Whh_l,
                       const float* __restrict__ Wg, const float* __restrict__ Wl,
                       f16* __restrict__ wfused, float* __restrict__ biasf,
                       u32* __restrict__ whhg, u32* __restrict__ whhl,
                       f16* __restrict__ wg16, f16* __restrict__ wl16) {
  const int tid = blockIdx.x * blockDim.x + threadIdx.x;
  const int stride = gridDim.x * blockDim.x;
  for (int i = tid; i < 1152 * 192; i += stride) {
    int r = i / 192;
    wfused[i] = (f16)(r < 768 ? Wih_g[i] : Wih_l[i - 768 * 192]);
  }
  for (int i = tid; i < 1152; i += stride)
    biasf[i] = (i < 768) ? bih_g[i] : bih_l[i - 768];
  for (int idx = tid; idx < 128 * 768; idx += stride) {
    int i = idx / 768, j = idx % 768;
    int g = j >> 2, s = j & 3, m = i >> 5, q = i & 31;
    int row = 4 * g + m, u = s * 32 + q;
    whhg[idx] = pk2f(Whh_g[row * 256 + 2 * u], Whh_g[row * 256 + 2 * u + 1]);
  }
  for (int idx = tid; idx < 64 * 384; idx += stride) {
    int i = idx / 384, j = idx % 384;
    int g = j >> 2, s = j & 3, m = i >> 4, q = i & 15;
    int row = 4 * g + m, u = s * 16 + q;
    whhl[idx] = pk2f(Whh_l[row * 128 + 2 * u], Whh_l[row * 128 + 2 * u + 1]);
  }
  for (int i = tid; i < 128 * 256; i += stride) wg16[i] = (f16)Wg[i];
  for (int i = tid; i < 64 * 128; i += stride) wl16[i] = (f16)Wl[i];
}

// ---------- copy f_seq -> inp cols 0..63 (u32), fully coalesced ----------
__global__ __launch_bounds__(256) void copy_f_k(const float* __restrict__ f_seq,
                                                f16* __restrict__ inp) {
  const size_t idx = (size_t)blockIdx.x * 256 + threadIdx.x;
  const float4 v = reinterpret_cast<const float4*>(f_seq)[idx];
  const size_t row = idx >> 5, c4 = idx & 31;
  uint2 pr; pr.x = pk2f(v.x, v.y); pr.y = pk2f(v.z, v.w);
  *reinterpret_cast<uint2*>(reinterpret_cast<u32*>(inp) + row * 96 + 2 * c4) = pr;
}

// ---------- copy delta -> inp cols 64..79 ----------
__global__ __launch_bounds__(256) void copy_d_k(const float* __restrict__ delta,
                                                f16* __restrict__ inp) {
  const size_t idx = (size_t)blockIdx.x * 256 + threadIdx.x;
  const float4 v = reinterpret_cast<const float4*>(delta)[idx];
  const size_t row = idx >> 3, c4 = idx & 7;
  uint2 pr; pr.x = pk2f(v.x, v.y); pr.y = pk2f(v.z, v.w);
  *reinterpret_cast<uint2*>(reinterpret_cast<u32*>(inp) + row * 96 + 64 + 2 * c4) = pr;
}

// ---------- ov encoder: silu(ov@W1^T+b1)@W2^T+b2 -> inp cols 80..95 ----------
__global__ __launch_bounds__(256) void ovenc_k(
    const float* __restrict__ ovin, const float* __restrict__ W1,
    const float* __restrict__ b1, const float* __restrict__ W2,
    const float* __restrict__ b2, f16* __restrict__ inp) {
  __shared__ float sW1[2048], sW2[2048], sb1[64], sb2[32];
  for (int i = threadIdx.x; i < 2048; i += 256) { sW1[i] = W1[i]; sW2[i] = W2[i]; }
  if (threadIdx.x < 64) sb1[threadIdx.x] = b1[threadIdx.x];
  if (threadIdx.x < 32) sb2[threadIdx.x] = b2[threadIdx.x];
  __syncthreads();
  const size_t row = (size_t)blockIdx.x * 256 + threadIdx.x;

  float ov[32];
  const float4* ovp = reinterpret_cast<const float4*>(ovin + row * 32);
#pragma unroll
  for (int i = 0; i < 8; ++i) {
    float4 v = ovp[i];
    ov[4 * i] = v.x; ov[4 * i + 1] = v.y; ov[4 * i + 2] = v.z; ov[4 * i + 3] = v.w;
  }
  float hb[64];
#pragma unroll
  for (int j = 0; j < 64; ++j) {
    float s = sb1[j];
#pragma unroll
    for (int k = 0; k < 32; ++k) s += sW1[j * 32 + k] * ov[k];
    hb[j] = s * sigf(s);
  }
  u32* orow = reinterpret_cast<u32*>(inp) + row * 96 + 80;
#pragma unroll
  for (int p = 0; p < 16; ++p) {
    float s0 = sb2[2 * p], s1 = sb2[2 * p + 1];
#pragma unroll
    for (int j = 0; j < 64; ++j) {
      s0 += sW2[(2 * p) * 64 + j] * hb[j];
      s1 += sW2[(2 * p + 1) * 64 + j] * hb[j];
    }
    orow[p] = pk2f(s0, s1);
  }
}

// ---------- MFMA f16 GEMM: C[M][N] = A[rows][K] @ Bw[N][K]^T + bias ----------
template <int K, int NROWSB, int NVALID, bool OUTF16, int LDC, bool REMAP>
__global__ __launch_bounds__(256, 2) void gemm_f16k(
    const f16* __restrict__ A, const f16* __restrict__ Bw,
    const float* __restrict__ bias, void* __restrict__ Cout, int t_base) {
  __shared__ alignas(16) f16 At[128 * 40];
  __shared__ alignas(16) f16 Bt[128 * 40];
  const int n0 = blockIdx.x * 128;
  const int m0 = blockIdx.y * 128;
  const int tid = threadIdx.x;
  const int l = tid & 63;
  const int w = tid >> 6;
  const int wm = w >> 1, wn = w & 1;
  const int srow = tid >> 2, schunk = tid & 3;

  f32x4 acc[4][4] = {};

  for (int k0 = 0; k0 < K; k0 += 32) {
#pragma unroll
    for (int hh = 0; hh < 2; ++hh) {
      int row = srow + hh * 64;
      int m = m0 + row;
      size_t g = REMAP ? ((size_t)(m & 255) * 512 + (size_t)t_base + (size_t)(m >> 8))
                       : (size_t)m;
      uint4 av = *reinterpret_cast<const uint4*>(A + g * K + k0 + schunk * 8);
      *reinterpret_cast<uint4*>(&At[row * 40 + schunk * 8]) = av;
      int nr = n0 + row;
      uint4 bv = make_uint4(0u, 0u, 0u, 0u);
      if (nr < NROWSB)
        bv = *reinterpret_cast<const uint4*>(Bw + (size_t)nr * K + k0 + schunk * 8);
      *reinterpret_cast<uint4*>(&Bt[row * 40 + schunk * 8]) = bv;
    }
    __syncthreads();
    f16x8 af[4], bf[4];
#pragma unroll
    for (int i = 0; i < 4; ++i) {
      af[i] = *reinterpret_cast<const f16x8*>(&At[(wm * 64 + i * 16 + (l & 15)) * 40 + (l >> 4) * 8]);
      bf[i] = *reinterpret_cast<const f16x8*>(&Bt[(wn * 64 + i * 16 + (l & 15)) * 40 + (l >> 4) * 8]);
    }
#pragma unroll
    for (int mi = 0; mi < 4; ++mi)
#pragma unroll
      for (int ni = 0; ni < 4; ++ni)
        acc[mi][ni] = __builtin_amdgcn_mfma_f32_16x16x32_f16(af[mi], bf[ni], acc[mi][ni], 0, 0, 0);
    __syncthreads();
  }

  const int mbase = m0 + wm * 64 + ((l >> 4) << 2);
  const int nbase = n0 + wn * 64 + (l & 15);
#pragma unroll
  for (int mi = 0; mi < 4; ++mi) {
#pragma unroll
    for (int ni = 0; ni < 4; ++ni) {
      int n = nbase + ni * 16;
      if (n < NVALID) {
        float bsv = bias[n];
#pragma unroll
        for (int q = 0; q < 4; ++q) {
          int m = mbase + mi * 16 + q;
          float v = acc[mi][ni][q] + bsv;
          if constexpr (OUTF16)
            reinterpret_cast<f16*>(Cout)[(size_t)m * LDC + n] = (f16)v;
          else
            reinterpret_cast<float*>(Cout)[(size_t)m * LDC + n] = v;
        }
      }
    }
  }
}

// ---------- global GRU scan chunk: 768 thr, 4-row x quarter-K split ----------
// thread j: g=j>>2, s=j&3; owns rows 4g+0..3 over h-u32 slice [32s,32s+32).
// After 4-lane transpose-reduce, lane j holds full gh of row j.
__global__ __launch_bounds__(768, 3) void gru_global_k(
    const u32* __restrict__ whh, const float* __restrict__ bhh,
    const f16* __restrict__ xbuf, u32* __restrict__ hseq,
    float* __restrict__ hstf, u32* __restrict__ hstp, int t0) {
  __shared__ alignas(16) u32 hpk[128];
  __shared__ float hfs[256];
  __shared__ float rz[512];
  const int b = blockIdx.x;
  const int r = threadIdx.x;
  const int s = r & 3;

  u32 wv[128];
#pragma unroll
  for (int i = 0; i < 128; ++i) wv[i] = whh[i * 768 + r];
#pragma unroll
  for (int i = 0; i < 128; ++i) asm volatile("" : "+v"(wv[i]));  // pin: no remat from L2
  const float bh = bhh[r];

  if (t0 == 0) {
    if (r < 256) hfs[r] = 0.f;
    if (r < 128) hpk[r] = 0u;
  } else {
    if (r < 256) hfs[r] = hstf[b * 256 + r];
    if (r < 128) hpk[r] = hstp[b * 128 + r];
  }
  __syncthreads();

  const f16* xp = xbuf + (size_t)b * 1152 + r;
  u32* hout = hseq + (size_t)b * 512 * 128 + (size_t)t0 * 128;
  const uint4* hpk4 = reinterpret_cast<const uint4*>(hpk);
  float xv = (float)xp[0];

  for (int t = 0; t < TC; ++t) {
    float xnext = 0.f;
    if (t < TC - 1) xnext = (float)xp[(size_t)(t + 1) * 256 * 1152];

    float a0 = 0.f, a1 = 0.f, a2 = 0.f, a3 = 0.f;
#pragma unroll
    for (int cc = 0; cc < 8; ++cc) {
      uint4 hq = hpk4[s * 8 + cc];   // 4 distinct 16B addrs per wave: conflict-light
      a0 = dot2f(wv[0 * 32 + cc * 4 + 0], hq.x, a0);
      a1 = dot2f(wv[1 * 32 + cc * 4 + 0], hq.x, a1);
      a2 = dot2f(wv[2 * 32 + cc * 4 + 0], hq.x, a2);
      a3 = dot2f(wv[3 * 32 + cc * 4 + 0], hq.x, a3);
      a0 = dot2f(wv[0 * 32 + cc * 4 + 1], hq.y, a0);
      a1 = dot2f(wv[1 * 32 + cc * 4 + 1], hq.y, a1);
      a2 = dot2f(wv[2 * 32 + cc * 4 + 1], hq.y, a2);
      a3 = dot2f(wv[3 * 32 + cc * 4 + 1], hq.y, a3);
      a0 = dot2f(wv[0 * 32 + cc * 4 + 2], hq.z, a0);
      a1 = dot2f(wv[1 * 32 + cc * 4 + 2], hq.z, a1);
      a2 = dot2f(wv[2 * 32 + cc * 4 + 2], hq.z, a2);
      a3 = dot2f(wv[3 * 32 + cc * 4 + 2], hq.z, a3);
      a0 = dot2f(wv[0 * 32 + cc * 4 + 3], hq.w, a0);
      a1 = dot2f(wv[1 * 32 + cc * 4 + 3], hq.w, a1);
      a2 = dot2f(wv[2 * 32 + cc * 4 + 3], hq.w, a2);
      a3 = dot2f(wv[3 * 32 + cc * 4 + 3], hq.w, a3);
    }
    // 4-lane transpose-reduce: all lanes in group get all 4 row-sums
    a0 += __shfl_xor(a0, 1, 64); a1 += __shfl_xor(a1, 1, 64);
    a2 += __shfl_xor(a2, 1, 64); a3 += __shfl_xor(a3, 1, 64);
    a0 += __shfl_xor(a0, 2, 64); a1 += __shfl_xor(a1, 2, 64);
    a2 += __shfl_xor(a2, 2, 64); a3 += __shfl_xor(a3, 2, 64);
    float gh = (s == 0 ? a0 : s == 1 ? a1 : s == 2 ? a2 : a3) + bh;

    if (r < 512) rz[r] = sigf(xv + gh);   // waves 0-7: r,z gates
    __syncthreads();
    if (r >= 512) {                        // waves 8-11: n gate + h update
      int j = r - 512;
      float rv = rz[j];
      float zv = rz[256 + j];
      float nv = tanhf_fast(xv + rv * gh);
      float hold = hfs[j];
      float hnew = (1.f - zv) * nv + zv * hold;
      hfs[j] = hnew;
      float hpart = __shfl_xor(hnew, 1, 64);
      if ((j & 1) == 0) {
        u32 packed = pk2f(hnew, hpart);
        hpk[j >> 1] = packed;
        hout[(size_t)t * 128 + (j >> 1)] = packed;
      }
    }
    __syncthreads();
    xv = xnext;
  }
  if (r < 256) hstf[b * 256 + r] = hfs[r];
  if (r < 128) hstp[b * 128 + r] = hpk[r];
}

// ---------- local GRU scan chunk: 384 thr, 4-row x quarter-K split ----------
__global__ __launch_bounds__(384, 3) void gru_local_k(
    const u32* __restrict__ whh, const float* __restrict__ bhh,
    const f16* __restrict__ xbuf, u32* __restrict__ hseq,
    float* __restrict__ hstf, u32* __restrict__ hstp, int t0) {
  __shared__ alignas(16) u32 hpk[64];
  __shared__ float hfs[128];
  __shared__ float rz[256];
  const int b = blockIdx.x;
  const int r = threadIdx.x;
  const int s = r & 3;

  u32 wv[64];
#pragma unroll
  for (int i = 0; i < 64; ++i) wv[i] = whh[i * 384 + r];
#pragma unroll
  for (int i = 0; i < 64; ++i) asm volatile("" : "+v"(wv[i]));
  const float bh = bhh[r];

  if (t0 == 0) {
    if (r < 128) hfs[r] = 0.f;
    if (r < 64) hpk[r] = 0u;
  } else {
    if (r < 128) hfs[r] = hstf[b * 128 + r];
    if (r < 64) hpk[r] = hstp[b * 64 + r];
  }
  __syncthreads();

  const f16* xp = xbuf + (size_t)b * 1152 + 768 + r;
  u32* hout = hseq + (size_t)b * 512 * 64 + (size_t)t0 * 64;
  const uint4* hpk4 = reinterpret_cast<const uint4*>(hpk);
  float xv = (float)xp[0];

  for (int t = 0; t < TC; ++t) {
    float xnext = 0.f;
    if (t < TC - 1) xnext = (float)xp[(size_t)(t + 1) * 256 * 1152];

    float a0 = 0.f, a1 = 0.f, a2 = 0.f, a3 = 0.f;
#pragma unroll
    for (int cc = 0; cc < 4; ++cc) {
      uint4 hq = hpk4[s * 4 + cc];
      a0 = dot2f(wv[0 * 16 + cc * 4 + 0], hq.x, a0);
      a1 = dot2f(wv[1 * 16 + cc * 4 + 0], hq.x, a1);
      a2 = dot2f(wv[2 * 16 + cc * 4 + 0], hq.x, a2);
      a3 = dot2f(wv[3 * 16 + cc * 4 + 0], hq.x, a3);
      a0 = dot2f(wv[0 * 16 + cc * 4 + 1], hq.y, a0);
      a1 = dot2f(wv[1 * 16 + cc * 4 + 1], hq.y, a1);
      a2 = dot2f(wv[2 * 16 + cc * 4 + 1], hq.y, a2);
      a3 = dot2f(wv[3 * 16 + cc * 4 + 1], hq.y, a3);
      a0 = dot2f(wv[0 * 16 + cc * 4 + 2], hq.z, a0);
      a1 = dot2f(wv[1 * 16 + cc * 4 + 2], hq.z, a1);
      a2 = dot2f(wv[2 * 16 + cc * 4 + 2], hq.z, a2);
      a3 = dot2f(wv[3 * 16 + cc * 4 + 2], hq.z, a3);
      a0 = dot2f(wv[0 * 16 + cc * 4 + 3], hq.w, a0);
      a1 = dot2f(wv[1 * 16 + cc * 4 + 3], hq.w, a1);
      a2 = dot2f(wv[2 * 16 + cc * 4 + 3], hq.w, a2);
      a3 = dot2f(wv[3 * 16 + cc * 4 + 3], hq.w, a3);
    }
    a0 += __shfl_xor(a0, 1, 64); a1 += __shfl_xor(a1, 1, 64);
    a2 += __shfl_xor(a2, 1, 64); a3 += __shfl_xor(a3, 1, 64);
    a0 += __shfl_xor(a0, 2, 64); a1 += __shfl_xor(a1, 2, 64);
    a2 += __shfl_xor(a2, 2, 64); a3 += __shfl_xor(a3, 2, 64);
    float gh = (s == 0 ? a0 : s == 1 ? a1 : s == 2 ? a2 : a3) + bh;

    if (r < 256) rz[r] = sigf(xv + gh);   // waves 0-3
    __syncthreads();
    if (r >= 256) {                        // waves 4-5
      int j = r - 256;
      float rv = rz[j];
      float zv = rz[128 + j];
      float nv = tanhf_fast(xv + rv * gh);
      float hold = hfs[j];
      float hnew = (1.f - zv) * nv + zv * hold;
      hfs[j] = hnew;
      float hpart = __shfl_xor(hnew, 1, 64);
      if ((j & 1) == 0) {
        u32 packed = pk2f(hnew, hpart);
        hpk[j >> 1] = packed;
        hout[(size_t)t * 64 + (j >> 1)] = packed;
      }
    }
    __syncthreads();
    xv = xnext;
  }
  if (r < 128) hstf[b * 128 + r] = hfs[r];
  if (r < 64) hstp[b * 64 + r] = hpk[r];
}

// ---------- launch ----------
extern "C" void kernel_launch(void* const* d_in, const int* in_sizes, int n_in,
                              void* d_out, int out_size, void* d_ws, size_t ws_size,
                              hipStream_t stream) {
  (void)in_sizes; (void)n_in; (void)out_size;
  if (ws_size < WS_NEED) return;
  const float* f_seq = (const float*)d_in[0];
  const float* delta = (const float*)d_in[1];
  const float* ovseq = (const float*)d_in[2];
  const float* W1 = (const float*)d_in[3];
  const float* b1 = (const float*)d_in[4];
  const float* W2 = (const float*)d_in[5];
  const float* b2 = (const float*)d_in[6];
  const float* Wih_g = (const float*)d_in[7];
  const float* Whh_g = (const float*)d_in[8];
  const float* bih_g = (const float*)d_in[9];
  const float* bhh_g = (const float*)d_in[10];
  const float* Wih_l = (const float*)d_in[11];
  const float* Whh_l = (const float*)d_in[12];
  const float* bih_l = (const float*)d_in[13];
  const float* bhh_l = (const float*)d_in[14];
  const float* Wg = (const float*)d_in[15];
  const float* bg = (const float*)d_in[16];
  const float* Wl = (const float*)d_in[17];
  const float* bl = (const float*)d_in[18];

  char* ws = (char*)d_ws;
  f16* inp = (f16*)(ws + O_INP);
  f16* xbuf = (f16*)(ws + O_XB);
  f16* hg16 = (f16*)(ws + O_HG);
  f16* hl16 = (f16*)(ws + O_HL);
  f16* wfused = (f16*)(ws + O_WF);
  float* biasf = (float*)(ws + O_BF);
  u32* whhg = (u32*)(ws + O_WHG);
  u32* whhl = (u32*)(ws + O_WHL);
  f16* wg16 = (f16*)(ws + O_WG);
  f16* wl16 = (f16*)(ws + O_WL);
  float* hgf = (float*)(ws + O_HGF);
  u32* hgp = (u32*)(ws + O_HGP);
  float* hlf = (float*)(ws + O_HLF);
  u32* hlp = (u32*)(ws + O_HLP);

  float* outg = (float*)d_out;
  float* outm = outg + NROWS * 128;

  prep_k<<<dim3(256), dim3(256), 0, stream>>>(Wih_g, Wih_l, bih_g, bih_l, Whh_g, Whh_l,
                                              Wg, Wl, wfused, biasf, whhg, whhl, wg16, wl16);
  copy_f_k<<<dim3(NROWS * 32 / 256), dim3(256), 0, stream>>>(f_seq, inp);
  copy_d_k<<<dim3(NROWS * 8 / 256), dim3(256), 0, stream>>>(delta, inp);
  ovenc_k<<<dim3(512), dim3(256), 0, stream>>>(ovseq, W1, b1, W2, b2, inp);

  for (int c = 0; c < NCHUNK; ++c) {
    gemm_f16k<192, 1152, 1152, true, 1152, true><<<dim3(9, CROWS / 128), dim3(256), 0, stream>>>(
        inp, wfused, biasf, xbuf, c * TC);
    gru_global_k<<<dim3(256), dim3(768), 0, stream>>>(whhg, bhh_g, xbuf, (u32*)hg16, hgf, hgp, c * TC);
    gru_local_k<<<dim3(256), dim3(384), 0, stream>>>(whhl, bhh_l, xbuf, (u32*)hl16, hlf, hlp, c * TC);
  }

  gemm_f16k<256, 128, 128, false, 128, false><<<dim3(1, 1024), dim3(256), 0, stream>>>(hg16, wg16, bg, outg, 0);
  gemm_f16k<128, 64, 64, false, 64, false><<<dim3(1, 1024), dim3(256), 0, stream>>>(hl16, wl16, bl, outm, 0);
}

// Round 9
// 1713.213 us; speedup vs baseline: 1.0425x; 1.0425x over previous
//
#include <hip/hip_runtime.h>

typedef _Float16 f16;
typedef _Float16 f16x2 __attribute__((ext_vector_type(2)));
typedef _Float16 f16x8 __attribute__((ext_vector_type(8)));
typedef float f32x4 __attribute__((ext_vector_type(4)));
typedef unsigned int u32;

// ---------- sizes ----------
// B=256, W=512, FEAT=128, TIME=32, OV=32, IN=192, HG=256, HL=128, OG=128, OL=64
static constexpr size_t NROWS = 131072;
static constexpr int TC = 64;
static constexpr int NCHUNK = 8;   // 512 / TC
static constexpr size_t CROWS = 256 * TC;  // rows per chunk = 16384

// inp is B-MAJOR: row (b*512 + t), 192 f16 (96 u32). xbuf rows m-order: m = tt*256 + b.
static constexpr size_t O_INP = 0;
static constexpr size_t SZ_INP = NROWS * 192 * 2;
static constexpr size_t O_XB  = O_INP + SZ_INP;
static constexpr size_t SZ_XB = CROWS * 1152 * 2;
static constexpr size_t O_HG  = O_XB + SZ_XB;
static constexpr size_t SZ_HG = NROWS * 256 * 2;
static constexpr size_t O_HL  = O_HG + SZ_HG;
static constexpr size_t SZ_HL = NROWS * 128 * 2;
static constexpr size_t O_WF  = O_HL + SZ_HL;
static constexpr size_t SZ_WF = 1152 * 192 * 2;
static constexpr size_t O_BF  = O_WF + SZ_WF;
static constexpr size_t SZ_BF = 1152 * 4;
static constexpr size_t O_WHG = O_BF + SZ_BF;     // whh_g thread-interleaved [128][768] u32
static constexpr size_t SZ_WHG = 128 * 768 * 4;
static constexpr size_t O_WHL = O_WHG + SZ_WHG;   // whh_l thread-interleaved [64][384] u32
static constexpr size_t SZ_WHL = 64 * 384 * 4;
static constexpr size_t O_WG  = O_WHL + SZ_WHL;
static constexpr size_t SZ_WG = 128 * 256 * 2;
static constexpr size_t O_WL  = O_WG + SZ_WG;
static constexpr size_t SZ_WL = 64 * 128 * 2;
static constexpr size_t O_HGF = O_WL + SZ_WL;
static constexpr size_t SZ_HGF = 256 * 256 * 4;
static constexpr size_t O_HGP = O_HGF + SZ_HGF;
static constexpr size_t SZ_HGP = 256 * 128 * 4;
static constexpr size_t O_HLF = O_HGP + SZ_HGP;
static constexpr size_t SZ_HLF = 256 * 128 * 4;
static constexpr size_t O_HLP = O_HLF + SZ_HLF;
static constexpr size_t SZ_HLP = 256 * 64 * 4;
static constexpr size_t WS_NEED = O_HLP + SZ_HLP; // ~181.5 MiB

// ---------- helpers ----------
__device__ inline u32 pk2f(float lo, float hi) {
  f16x2 t; t.x = (f16)lo; t.y = (f16)hi;
  return __builtin_bit_cast(u32, t);
}

#if defined(__has_builtin)
#if __has_builtin(__builtin_amdgcn_fdot2)
#define HAVE_FDOT2 1
#endif
#endif

__device__ inline float dot2f(u32 w, u32 h, float c) {
#ifdef HAVE_FDOT2
  return __builtin_amdgcn_fdot2(__builtin_bit_cast(f16x2, w),
                                __builtin_bit_cast(f16x2, h), c, false);
#else
  f16x2 a = __builtin_bit_cast(f16x2, w);
  f16x2 b = __builtin_bit_cast(f16x2, h);
  return c + (float)a.x * (float)b.x + (float)a.y * (float)b.y;
#endif
}

__device__ inline float sigf(float x) { return 1.f / (1.f + __expf(-x)); }
__device__ inline float tanhf_fast(float x) { return 1.f - 2.f / (1.f + __expf(2.f * x)); }

// ---------- prep: weight conversion/packing ----------
// Scan weights THREAD-INTERLEAVED for the 4-row x quarter-K split (see gru_*_k).
__global__ void prep_k(const float* __restrict__ Wih_g, const float* __restrict__ Wih_l,
                       const float* __restrict__ bih_g, const float* __restrict__ bih_l,
                       const float* __restrict__ Whh_g, const float* __restrict__ Whh_l,
                       const float* __restrict__ Wg, const float* __restrict__ Wl,
                       f16* __restrict__ wfused, float* __restrict__ biasf,
                       u32* __restrict__ whhg, u32* __restrict__ whhl,
                       f16* __restrict__ wg16, f16* __restrict__ wl16) {
  const int tid = blockIdx.x * blockDim.x + threadIdx.x;
  const int stride = gridDim.x * blockDim.x;
  for (int i = tid; i < 1152 * 192; i += stride) {
    int r = i / 192;
    wfused[i] = (f16)(r < 768 ? Wih_g[i] : Wih_l[i - 768 * 192]);
  }
  for (int i = tid; i < 1152; i += stride)
    biasf[i] = (i < 768) ? bih_g[i] : bih_l[i - 768];
  for (int idx = tid; idx < 128 * 768; idx += stride) {
    int i = idx / 768, j = idx % 768;
    int g = j >> 2, s = j & 3, m = i >> 5, q = i & 31;
    int row = 4 * g + m, u = s * 32 + q;
    whhg[idx] = pk2f(Whh_g[row * 256 + 2 * u], Whh_g[row * 256 + 2 * u + 1]);
  }
  for (int idx = tid; idx < 64 * 384; idx += stride) {
    int i = idx / 384, j = idx % 384;
    int g = j >> 2, s = j & 3, m = i >> 4, q = i & 15;
    int row = 4 * g + m, u = s * 16 + q;
    whhl[idx] = pk2f(Whh_l[row * 128 + 2 * u], Whh_l[row * 128 + 2 * u + 1]);
  }
  for (int i = tid; i < 128 * 256; i += stride) wg16[i] = (f16)Wg[i];
  for (int i = tid; i < 64 * 128; i += stride) wl16[i] = (f16)Wl[i];
}

// ---------- copy f_seq -> inp cols 0..63 (u32), fully coalesced ----------
__global__ __launch_bounds__(256) void copy_f_k(const float* __restrict__ f_seq,
                                                f16* __restrict__ inp) {
  const size_t idx = (size_t)blockIdx.x * 256 + threadIdx.x;
  const float4 v = reinterpret_cast<const float4*>(f_seq)[idx];
  const size_t row = idx >> 5, c4 = idx & 31;
  uint2 pr; pr.x = pk2f(v.x, v.y); pr.y = pk2f(v.z, v.w);
  *reinterpret_cast<uint2*>(reinterpret_cast<u32*>(inp) + row * 96 + 2 * c4) = pr;
}

// ---------- copy delta -> inp cols 64..79 ----------
__global__ __launch_bounds__(256) void copy_d_k(const float* __restrict__ delta,
                                                f16* __restrict__ inp) {
  const size_t idx = (size_t)blockIdx.x * 256 + threadIdx.x;
  const float4 v = reinterpret_cast<const float4*>(delta)[idx];
  const size_t row = idx >> 3, c4 = idx & 7;
  uint2 pr; pr.x = pk2f(v.x, v.y); pr.y = pk2f(v.z, v.w);
  *reinterpret_cast<uint2*>(reinterpret_cast<u32*>(inp) + row * 96 + 64 + 2 * c4) = pr;
}

// ---------- ov encoder: 16 threads/row, 16 rows/block, 2-stage LDS MLP ----------
// silu(ov@W1^T+b1)@W2^T+b2 -> inp cols 80..95.
__global__ __launch_bounds__(256) void ovenc_k(
    const float* __restrict__ ovin, const float* __restrict__ W1,
    const float* __restrict__ b1, const float* __restrict__ W2,
    const float* __restrict__ b2, f16* __restrict__ inp) {
  __shared__ float sW1T[32 * 64];   // [k][j] transposed: bank-conflict-free stage-1 reads
  __shared__ float sW2T[64 * 32];   // [j][p] transposed: float2 reads, banks 0..31
  __shared__ float sb1[64], sb2[32];
  __shared__ float sOV[16][33];     // stride 33: distinct banks across rows
  __shared__ float sHB[16][80];     // stride 80: 2-way (free) on reads/writes
  const int tid = threadIdx.x;
  for (int i = tid; i < 2048; i += 256) {
    int j = i >> 5, k = i & 31;
    sW1T[k * 64 + j] = W1[i];        // W1[j][k]
    int p = i >> 6, jj = i & 63;
    sW2T[jj * 32 + p] = W2[i];       // W2[p][jj]
  }
  if (tid < 64) sb1[tid] = b1[tid];
  if (tid < 32) sb2[tid] = b2[tid];
  const int rl = tid >> 4;          // row within block (0..15)
  const int ln = tid & 15;          // lane within row  (0..15)
  const size_t row = (size_t)blockIdx.x * 16 + rl;
  {
    float2 v = reinterpret_cast<const float2*>(ovin + row * 32)[ln];
    sOV[rl][2 * ln] = v.x; sOV[rl][2 * ln + 1] = v.y;
  }
  __syncthreads();
  // stage 1: hidden j = ln + 16m (4 per thread)
  float hbv[4];
#pragma unroll
  for (int m = 0; m < 4; ++m) {
    const int j = ln + 16 * m;
    float s = sb1[j];
#pragma unroll
    for (int k = 0; k < 32; ++k) s += sW1T[k * 64 + j] * sOV[rl][k];
    hbv[m] = s * sigf(s);            // SiLU
  }
#pragma unroll
  for (int m = 0; m < 4; ++m) sHB[rl][ln + 16 * m] = hbv[m];
  __syncthreads();
  // stage 2: output pair (2ln, 2ln+1)
  float s0 = sb2[2 * ln], s1 = sb2[2 * ln + 1];
#pragma unroll
  for (int j = 0; j < 64; ++j) {
    const float hv = sHB[rl][j];
    const float2 w2 = *reinterpret_cast<const float2*>(&sW2T[j * 32 + 2 * ln]);
    s0 += w2.x * hv;
    s1 += w2.y * hv;
  }
  reinterpret_cast<u32*>(inp)[row * 96 + 80 + ln] = pk2f(s0, s1);
}

// ---------- MFMA f16 GEMM: C[M][N] = A[rows][K] @ Bw[N][K]^T + bias ----------
template <int K, int NROWSB, int NVALID, bool OUTF16, int LDC, bool REMAP>
__global__ __launch_bounds__(256, 2) void gemm_f16k(
    const f16* __restrict__ A, const f16* __restrict__ Bw,
    const float* __restrict__ bias, void* __restrict__ Cout, int t_base) {
  __shared__ alignas(16) f16 At[128 * 40];
  __shared__ alignas(16) f16 Bt[128 * 40];
  const int n0 = blockIdx.x * 128;
  const int m0 = blockIdx.y * 128;
  const int tid = threadIdx.x;
  const int l = tid & 63;
  const int w = tid >> 6;
  const int wm = w >> 1, wn = w & 1;
  const int srow = tid >> 2, schunk = tid & 3;

  f32x4 acc[4][4] = {};

  for (int k0 = 0; k0 < K; k0 += 32) {
#pragma unroll
    for (int hh = 0; hh < 2; ++hh) {
      int row = srow + hh * 64;
      int m = m0 + row;
      size_t g = REMAP ? ((size_t)(m & 255) * 512 + (size_t)t_base + (size_t)(m >> 8))
                       : (size_t)m;
      uint4 av = *reinterpret_cast<const uint4*>(A + g * K + k0 + schunk * 8);
      *reinterpret_cast<uint4*>(&At[row * 40 + schunk * 8]) = av;
      int nr = n0 + row;
      uint4 bv = make_uint4(0u, 0u, 0u, 0u);
      if (nr < NROWSB)
        bv = *reinterpret_cast<const uint4*>(Bw + (size_t)nr * K + k0 + schunk * 8);
      *reinterpret_cast<uint4*>(&Bt[row * 40 + schunk * 8]) = bv;
    }
    __syncthreads();
    f16x8 af[4], bf[4];
#pragma unroll
    for (int i = 0; i < 4; ++i) {
      af[i] = *reinterpret_cast<const f16x8*>(&At[(wm * 64 + i * 16 + (l & 15)) * 40 + (l >> 4) * 8]);
      bf[i] = *reinterpret_cast<const f16x8*>(&Bt[(wn * 64 + i * 16 + (l & 15)) * 40 + (l >> 4) * 8]);
    }
#pragma unroll
    for (int mi = 0; mi < 4; ++mi)
#pragma unroll
      for (int ni = 0; ni < 4; ++ni)
        acc[mi][ni] = __builtin_amdgcn_mfma_f32_16x16x32_f16(af[mi], bf[ni], acc[mi][ni], 0, 0, 0);
    __syncthreads();
  }

  const int mbase = m0 + wm * 64 + ((l >> 4) << 2);
  const int nbase = n0 + wn * 64 + (l & 15);
#pragma unroll
  for (int mi = 0; mi < 4; ++mi) {
#pragma unroll
    for (int ni = 0; ni < 4; ++ni) {
      int n = nbase + ni * 16;
      if (n < NVALID) {
        float bsv = bias[n];
#pragma unroll
        for (int q = 0; q < 4; ++q) {
          int m = mbase + mi * 16 + q;
          float v = acc[mi][ni][q] + bsv;
          if constexpr (OUTF16)
            reinterpret_cast<f16*>(Cout)[(size_t)m * LDC + n] = (f16)v;
          else
            reinterpret_cast<float*>(Cout)[(size_t)m * LDC + n] = v;
        }
      }
    }
  }
}

// ---------- global GRU scan chunk: 768 thr, 4-row x quarter-K split ----------
// thread j: g=j>>2, s=j&3; owns rows 4g+0..3 over h-u32 slice [32s,32s+32).
__global__ __launch_bounds__(768, 3) void gru_global_k(
    const u32* __restrict__ whh, const float* __restrict__ bhh,
    const f16* __restrict__ xbuf, u32* __restrict__ hseq,
    float* __restrict__ hstf, u32* __restrict__ hstp, int t0) {
  __shared__ alignas(16) u32 hpk[128];
  __shared__ float hfs[256];
  __shared__ float rz[512];
  const int b = blockIdx.x;
  const int r = threadIdx.x;
  const int s = r & 3;

  u32 wv[128];
#pragma unroll
  for (int i = 0; i < 128; ++i) wv[i] = whh[i * 768 + r];
#pragma unroll
  for (int i = 0; i < 128; ++i) asm volatile("" : "+v"(wv[i]));  // pin: no remat from L2
  const float bh = bhh[r];

  if (t0 == 0) {
    if (r < 256) hfs[r] = 0.f;
    if (r < 128) hpk[r] = 0u;
  } else {
    if (r < 256) hfs[r] = hstf[b * 256 + r];
    if (r < 128) hpk[r] = hstp[b * 128 + r];
  }
  __syncthreads();

  const f16* xp = xbuf + (size_t)b * 1152 + r;
  u32* hout = hseq + (size_t)b * 512 * 128 + (size_t)t0 * 128;
  const uint4* hpk4 = reinterpret_cast<const uint4*>(hpk);
  float xv = (float)xp[0];

  for (int t = 0; t < TC; ++t) {
    float xnext = 0.f;
    if (t < TC - 1) xnext = (float)xp[(size_t)(t + 1) * 256 * 1152];

    float a0 = 0.f, a1 = 0.f, a2 = 0.f, a3 = 0.f;
#pragma unroll
    for (int cc = 0; cc < 8; ++cc) {
      uint4 hq = hpk4[s * 8 + cc];   // 4 distinct 16B addrs per wave
      a0 = dot2f(wv[0 * 32 + cc * 4 + 0], hq.x, a0);
      a1 = dot2f(wv[1 * 32 + cc * 4 + 0], hq.x, a1);
      a2 = dot2f(wv[2 * 32 + cc * 4 + 0], hq.x, a2);
      a3 = dot2f(wv[3 * 32 + cc * 4 + 0], hq.x, a3);
      a0 = dot2f(wv[0 * 32 + cc * 4 + 1], hq.y, a0);
      a1 = dot2f(wv[1 * 32 + cc * 4 + 1], hq.y, a1);
      a2 = dot2f(wv[2 * 32 + cc * 4 + 1], hq.y, a2);
      a3 = dot2f(wv[3 * 32 + cc * 4 + 1], hq.y, a3);
      a0 = dot2f(wv[0 * 32 + cc * 4 + 2], hq.z, a0);
      a1 = dot2f(wv[1 * 32 + cc * 4 + 2], hq.z, a1);
      a2 = dot2f(wv[2 * 32 + cc * 4 + 2], hq.z, a2);
      a3 = dot2f(wv[3 * 32 + cc * 4 + 2], hq.z, a3);
      a0 = dot2f(wv[0 * 32 + cc * 4 + 3], hq.w, a0);
      a1 = dot2f(wv[1 * 32 + cc * 4 + 3], hq.w, a1);
      a2 = dot2f(wv[2 * 32 + cc * 4 + 3], hq.w, a2);
      a3 = dot2f(wv[3 * 32 + cc * 4 + 3], hq.w, a3);
    }
    a0 += __shfl_xor(a0, 1, 64); a1 += __shfl_xor(a1, 1, 64);
    a2 += __shfl_xor(a2, 1, 64); a3 += __shfl_xor(a3, 1, 64);
    a0 += __shfl_xor(a0, 2, 64); a1 += __shfl_xor(a1, 2, 64);
    a2 += __shfl_xor(a2, 2, 64); a3 += __shfl_xor(a3, 2, 64);
    float gh = (s == 0 ? a0 : s == 1 ? a1 : s == 2 ? a2 : a3) + bh;

    if (r < 512) rz[r] = sigf(xv + gh);   // waves 0-7: r,z gates
    __syncthreads();
    if (r >= 512) {                        // waves 8-11: n gate + h update
      int j = r - 512;
      float rv = rz[j];
      float zv = rz[256 + j];
      float nv = tanhf_fast(xv + rv * gh);
      float hold = hfs[j];
      float hnew = (1.f - zv) * nv + zv * hold;
      hfs[j] = hnew;
      float hpart = __shfl_xor(hnew, 1, 64);
      if ((j & 1) == 0) {
        u32 packed = pk2f(hnew, hpart);
        hpk[j >> 1] = packed;
        hout[(size_t)t * 128 + (j >> 1)] = packed;
      }
    }
    __syncthreads();
    xv = xnext;
  }
  if (r < 256) hstf[b * 256 + r] = hfs[r];
  if (r < 128) hstp[b * 128 + r] = hpk[r];
}

// ---------- local GRU scan chunk: 384 thr, 4-row x quarter-K split ----------
__global__ __launch_bounds__(384, 3) void gru_local_k(
    const u32* __restrict__ whh, const float* __restrict__ bhh,
    const f16* __restrict__ xbuf, u32* __restrict__ hseq,
    float* __restrict__ hstf, u32* __restrict__ hstp, int t0) {
  __shared__ alignas(16) u32 hpk[64];
  __shared__ float hfs[128];
  __shared__ float rz[256];
  const int b = blockIdx.x;
  const int r = threadIdx.x;
  const int s = r & 3;

  u32 wv[64];
#pragma unroll
  for (int i = 0; i < 64; ++i) wv[i] = whh[i * 384 + r];
#pragma unroll
  for (int i = 0; i < 64; ++i) asm volatile("" : "+v"(wv[i]));
  const float bh = bhh[r];

  if (t0 == 0) {
    if (r < 128) hfs[r] = 0.f;
    if (r < 64) hpk[r] = 0u;
  } else {
    if (r < 128) hfs[r] = hstf[b * 128 + r];
    if (r < 64) hpk[r] = hstp[b * 64 + r];
  }
  __syncthreads();

  const f16* xp = xbuf + (size_t)b * 1152 + 768 + r;
  u32* hout = hseq + (size_t)b * 512 * 64 + (size_t)t0 * 64;
  const uint4* hpk4 = reinterpret_cast<const uint4*>(hpk);
  float xv = (float)xp[0];

  for (int t = 0; t < TC; ++t) {
    float xnext = 0.f;
    if (t < TC - 1) xnext = (float)xp[(size_t)(t + 1) * 256 * 1152];

    float a0 = 0.f, a1 = 0.f, a2 = 0.f, a3 = 0.f;
#pragma unroll
    for (int cc = 0; cc < 4; ++cc) {
      uint4 hq = hpk4[s * 4 + cc];
      a0 = dot2f(wv[0 * 16 + cc * 4 + 0], hq.x, a0);
      a1 = dot2f(wv[1 * 16 + cc * 4 + 0], hq.x, a1);
      a2 = dot2f(wv[2 * 16 + cc * 4 + 0], hq.x, a2);
      a3 = dot2f(wv[3 * 16 + cc * 4 + 0], hq.x, a3);
      a0 = dot2f(wv[0 * 16 + cc * 4 + 1], hq.y, a0);
      a1 = dot2f(wv[1 * 16 + cc * 4 + 1], hq.y, a1);
      a2 = dot2f(wv[2 * 16 + cc * 4 + 1], hq.y, a2);
      a3 = dot2f(wv[3 * 16 + cc * 4 + 1], hq.y, a3);
      a0 = dot2f(wv[0 * 16 + cc * 4 + 2], hq.z, a0);
      a1 = dot2f(wv[1 * 16 + cc * 4 + 2], hq.z, a1);
      a2 = dot2f(wv[2 * 16 + cc * 4 + 2], hq.z, a2);
      a3 = dot2f(wv[3 * 16 + cc * 4 + 2], hq.z, a3);
      a0 = dot2f(wv[0 * 16 + cc * 4 + 3], hq.w, a0);
      a1 = dot2f(wv[1 * 16 + cc * 4 + 3], hq.w, a1);
      a2 = dot2f(wv[2 * 16 + cc * 4 + 3], hq.w, a2);
      a3 = dot2f(wv[3 * 16 + cc * 4 + 3], hq.w, a3);
    }
    a0 += __shfl_xor(a0, 1, 64); a1 += __shfl_xor(a1, 1, 64);
    a2 += __shfl_xor(a2, 1, 64); a3 += __shfl_xor(a3, 1, 64);
    a0 += __shfl_xor(a0, 2, 64); a1 += __shfl_xor(a1, 2, 64);
    a2 += __shfl_xor(a2, 2, 64); a3 += __shfl_xor(a3, 2, 64);
    float gh = (s == 0 ? a0 : s == 1 ? a1 : s == 2 ? a2 : a3) + bh;

    if (r < 256) rz[r] = sigf(xv + gh);   // waves 0-3
    __syncthreads();
    if (r >= 256) {                        // waves 4-5
      int j = r - 256;
      float rv = rz[j];
      float zv = rz[128 + j];
      float nv = tanhf_fast(xv + rv * gh);
      float hold = hfs[j];
      float hnew = (1.f - zv) * nv + zv * hold;
      hfs[j] = hnew;
      float hpart = __shfl_xor(hnew, 1, 64);
      if ((j & 1) == 0) {
        u32 packed = pk2f(hnew, hpart);
        hpk[j >> 1] = packed;
        hout[(size_t)t * 64 + (j >> 1)] = packed;
      }
    }
    __syncthreads();
    xv = xnext;
  }
  if (r < 128) hstf[b * 128 + r] = hfs[r];
  if (r < 64) hstp[b * 64 + r] = hpk[r];
}

// ---------- launch ----------
extern "C" void kernel_launch(void* const* d_in, const int* in_sizes, int n_in,
                              void* d_out, int out_size, void* d_ws, size_t ws_size,
                              hipStream_t stream) {
  (void)in_sizes; (void)n_in; (void)out_size;
  if (ws_size < WS_NEED) return;
  const float* f_seq = (const float*)d_in[0];
  const float* delta = (const float*)d_in[1];
  const float* ovseq = (const float*)d_in[2];
  const float* W1 = (const float*)d_in[3];
  const float* b1 = (const float*)d_in[4];
  const float* W2 = (const float*)d_in[5];
  const float* b2 = (const float*)d_in[6];
  const float* Wih_g = (const float*)d_in[7];
  const float* Whh_g = (const float*)d_in[8];
  const float* bih_g = (const float*)d_in[9];
  const float* bhh_g = (const float*)d_in[10];
  const float* Wih_l = (const float*)d_in[11];
  const float* Whh_l = (const float*)d_in[12];
  const float* bih_l = (const float*)d_in[13];
  const float* bhh_l = (const float*)d_in[14];
  const float* Wg = (const float*)d_in[15];
  const float* bg = (const float*)d_in[16];
  const float* Wl = (const float*)d_in[17];
  const float* bl = (const float*)d_in[18];

  char* ws = (char*)d_ws;
  f16* inp = (f16*)(ws + O_INP);
  f16* xbuf = (f16*)(ws + O_XB);
  f16* hg16 = (f16*)(ws + O_HG);
  f16* hl16 = (f16*)(ws + O_HL);
  f16* wfused = (f16*)(ws + O_WF);
  float* biasf = (float*)(ws + O_BF);
  u32* whhg = (u32*)(ws + O_WHG);
  u32* whhl = (u32*)(ws + O_WHL);
  f16* wg16 = (f16*)(ws + O_WG);
  f16* wl16 = (f16*)(ws + O_WL);
  float* hgf = (float*)(ws + O_HGF);
  u32* hgp = (u32*)(ws + O_HGP);
  float* hlf = (float*)(ws + O_HLF);
  u32* hlp = (u32*)(ws + O_HLP);

  float* outg = (float*)d_out;
  float* outm = outg + NROWS * 128;

  prep_k<<<dim3(256), dim3(256), 0, stream>>>(Wih_g, Wih_l, bih_g, bih_l, Whh_g, Whh_l,
                                              Wg, Wl, wfused, biasf, whhg, whhl, wg16, wl16);
  copy_f_k<<<dim3(NROWS * 32 / 256), dim3(256), 0, stream>>>(f_seq, inp);
  copy_d_k<<<dim3(NROWS * 8 / 256), dim3(256), 0, stream>>>(delta, inp);
  ovenc_k<<<dim3(NROWS / 16), dim3(256), 0, stream>>>(ovseq, W1, b1, W2, b2, inp);

  for (int c = 0; c < NCHUNK; ++c) {
    gemm_f16k<192, 1152, 1152, true, 1152, true><<<dim3(9, CROWS / 128), dim3(256), 0, stream>>>(
        inp, wfused, biasf, xbuf, c * TC);
    gru_global_k<<<dim3(256), dim3(768), 0, stream>>>(whhg, bhh_g, xbuf, (u32*)hg16, hgf, hgp, c * TC);
    gru_local_k<<<dim3(256), dim3(384), 0, stream>>>(whhl, bhh_l, xbuf, (u32*)hl16, hlf, hlp, c * TC);
  }

  gemm_f16k<256, 128, 128, false, 128, false><<<dim3(1, 1024), dim3(256), 0, stream>>>(hg16, wg16, bg, outg, 0);
  gemm_f16k<128, 64, 64, false, 64, false><<<dim3(1, 1024), dim3(256), 0, stream>>>(hl16, wl16, bl, outm, 0);
}